// Round 2
// baseline (1357.544 us; speedup 1.0000x reference)
//
#include <hip/hip_runtime.h>
#include <hip/hip_bf16.h>

// QwenMoe: T=1024 H=2048 I=1408 E=60 SI=5632 topk=4, all inputs fp32, out fp32.
// fp32 router (exact top-k) + sparse grouped bf16-MFMA GEMMs.
// R2: 2-phase double-buffered K-loop (T3-minimum recipe) — one barrier per
// K-step, raw-fp32 reg staging so the vmcnt wait lands AFTER the MFMAs.

typedef float  f32x4  __attribute__((ext_vector_type(4)));
typedef short  bf16x8 __attribute__((ext_vector_type(8)));
typedef unsigned short u16;
typedef unsigned int   u32;

constexpr int TT = 1024, HD = 2048, ID = 1408, NE = 60, SID = 5632, KTOP = 4;

__device__ __forceinline__ u16 f2bf(float f) {
    union { float f; u32 u; } v; v.f = f;
    u32 r = v.u + 0x7FFFu + ((v.u >> 16) & 1u);   // RNE
    return (u16)(r >> 16);
}
__device__ __forceinline__ float bf2f(u16 b) {
    union { float f; u32 u; } v; v.u = ((u32)b) << 16; return v.f;
}
__device__ __forceinline__ uint4 pack8(float4 a, float4 b) {
    uint4 r;
    r.x = (u32)f2bf(a.x) | ((u32)f2bf(a.y) << 16);
    r.y = (u32)f2bf(a.z) | ((u32)f2bf(a.w) << 16);
    r.z = (u32)f2bf(b.x) | ((u32)f2bf(b.y) << 16);
    r.w = (u32)f2bf(b.z) | ((u32)f2bf(b.w) << 16);
    return r;
}
// LDS chunk swizzle: 4 chunks of 8 bf16 per 32-elem row; spreads b128 reads.
__device__ __forceinline__ int swz(int row, int c) { return c ^ ((row ^ (row >> 2)) & 3); }

// ---------------- router ----------------
__global__ __launch_bounds__(64) void router_k(
    const float* __restrict__ x, const float* __restrict__ rw,
    const float* __restrict__ sgw,
    float* __restrict__ topk_p, int* __restrict__ topk_i,
    int* __restrict__ cnt, float* __restrict__ sgate)
{
    const int t = blockIdx.x, l = threadIdx.x;
    const float4* xr = ((const float4*)(x + (size_t)t * HD)) + l * 8;
    float4 xa[8];
    #pragma unroll
    for (int i = 0; i < 8; i++) xa[i] = xr[i];

    float le = 0.f;
    for (int e = 0; e < NE; e++) {
        const float4* wr = ((const float4*)(rw + (size_t)e * HD)) + l * 8;
        float a = 0.f;
        #pragma unroll
        for (int i = 0; i < 8; i++) {
            float4 wv = wr[i];
            a += xa[i].x * wv.x + xa[i].y * wv.y + xa[i].z * wv.z + xa[i].w * wv.w;
        }
        #pragma unroll
        for (int s = 32; s; s >>= 1) a += __shfl_xor(a, s);
        if (l == e) le = a;
    }
    {
        const float4* wr = ((const float4*)sgw) + l * 8;
        float a = 0.f;
        #pragma unroll
        for (int i = 0; i < 8; i++) {
            float4 wv = wr[i];
            a += xa[i].x * wv.x + xa[i].y * wv.y + xa[i].z * wv.z + xa[i].w * wv.w;
        }
        #pragma unroll
        for (int s = 32; s; s >>= 1) a += __shfl_xor(a, s);
        if (l == 0) sgate[t] = 1.f / (1.f + __expf(-a));
    }
    float mv = (l < NE) ? le : -3.4e38f;
    #pragma unroll
    for (int s = 32; s; s >>= 1) mv = fmaxf(mv, __shfl_xor(mv, s));
    float p = (l < NE) ? __expf(le - mv) : 0.f;
    float ss = p;
    #pragma unroll
    for (int s = 32; s; s >>= 1) ss += __shfl_xor(ss, s);
    p /= ss;
    float pv = (l < NE) ? p : -1.f;
    int   pi = l;
    float kp = 0.f; int ki = 0;
    for (int k = 0; k < KTOP; k++) {
        float bv = pv; int bi = pi;
        #pragma unroll
        for (int s = 32; s; s >>= 1) {
            float ov = __shfl_xor(bv, s); int oi = __shfl_xor(bi, s);
            if (ov > bv || (ov == bv && oi < bi)) { bv = ov; bi = oi; }
        }
        if (l == k) { kp = bv; ki = bi; }
        if (pi == bi) pv = -1.f;
    }
    if (l < KTOP) {
        topk_p[t * KTOP + l] = kp;
        topk_i[t * KTOP + l] = ki;
        atomicAdd(&cnt[ki], 1);
    }
}

__global__ __launch_bounds__(64) void prefix_k(const int* __restrict__ cnt, int* __restrict__ base)
{
    int l = threadIdx.x;
    if (l < NE) {
        int s = 0;
        for (int j = 0; j < l; j++) s += cnt[j];
        base[l] = s;
    }
}

__global__ __launch_bounds__(256) void scatter_k(
    const float* __restrict__ topk_p, const int* __restrict__ topk_i,
    const int* __restrict__ base, int* __restrict__ fill,
    int* __restrict__ slot_tok, float* __restrict__ slot_wt)
{
    int t = blockIdx.x * blockDim.x + threadIdx.x;
    if (t >= TT) return;
    for (int k = 0; k < KTOP; k++) {
        int e = topk_i[t * KTOP + k];
        int pos = atomicAdd(&fill[e], 1);
        int s = base[e] + pos;
        slot_tok[s] = t;
        slot_wt[s]  = topk_p[t * KTOP + k];
    }
}

// ---------------- 128x128x32 bf16-MFMA GEMM, A[M][K] * B[N][K]^T ---------------
// MODE 0: C_bf16 = acc                       (gate pre-activations)
// MODE 1: C_bf16 = silu(G)*acc*scale         (up proj, fused SwiGLU + combine weight)
// MODE 2: out_f32 = sgate[row]*acc           (shared down, full overwrite)
// MODE 3: atomicAdd(out[slot_tok[row]], acc) (routed down, accumulate)
template<int MODE, bool ABF16, bool GROUPED>
__global__ __launch_bounds__(256) void gemm_k(
    const float* __restrict__ Af32, const u16* __restrict__ Abf16,
    const float* __restrict__ Bbase, size_t bStride,
    u16* __restrict__ Cbf, const u16* __restrict__ Gbf,
    float* __restrict__ outF,
    const int* __restrict__ slot_tok, const float* __restrict__ slot_wt,
    const float* __restrict__ sgate,
    const int* __restrict__ cnt, const int* __restrict__ basearr,
    int K, int N, int TR)
{
    __shared__ u16 Asl[2][128 * 32];
    __shared__ u16 Bsl[2][128 * 32];

    const int tid  = threadIdx.x;
    const int e    = GROUPED ? blockIdx.z : 0;
    const int mcnt = GROUPED ? cnt[e] : TR;
    const int mbase = GROUPED ? basearr[e] : 0;
    const float* Bp = Bbase + (size_t)e * bStride;

    const int srow  = tid >> 1;          // staging row 0..127
    const int skoff = (tid & 1) * 16;    // staging k offset (0 or 16)
    const int w = tid >> 6, l = tid & 63;
    const int wm0 = (w >> 1) * 64, wn0 = (w & 1) * 64;
    const int lm = l & 15, lk = l >> 4;
    const int brow = blockIdx.x * 128 + srow;
    const float* browp = Bp + (size_t)brow * K + skoff;

    // precomputed LDS offsets (elements)
    const int c0  = (tid & 1) * 2;
    const int wo0 = srow * 32 + (swz(srow, c0) << 3);
    const int wo1 = srow * 32 + (swz(srow, c0 + 1) << 3);
    int roA[4], roB[4];
    #pragma unroll
    for (int f = 0; f < 4; f++) {
        int ra = wm0 + f * 16 + lm;
        roA[f] = ra * 32 + (swz(ra, lk) << 3);
        int rb = wn0 + f * 16 + lm;
        roB[f] = rb * 32 + (swz(rb, lk) << 3);
    }

    const int nk = K >> 5;

    for (int mt = blockIdx.y; mt * 128 < mcnt; mt += gridDim.y) {
        const bool avalid = (mt * 128 + srow) < mcnt;
        const int  slotr  = mbase + mt * 128 + srow;
        size_t agrow;
        if constexpr (ABF16)        agrow = (size_t)slotr;
        else if constexpr (GROUPED) agrow = avalid ? (size_t)slot_tok[slotr] : 0;
        else                        agrow = (size_t)slotr;
        const float* arow_f = ABF16 ? nullptr : (Af32 + agrow * (size_t)K + skoff);
        const u16*   arow_b = ABF16 ? (Abf16 + agrow * (size_t)K + skoff) : nullptr;

        f32x4 acc[4][4];
        #pragma unroll
        for (int mf = 0; mf < 4; mf++)
            #pragma unroll
            for (int nf = 0; nf < 4; nf++)
                acc[mf][nf] = f32x4{0.f, 0.f, 0.f, 0.f};

        // raw staging registers (fp32 kept raw so vmcnt waits happen at write)
        float4 fa0, fa1, fa2, fa3;
        uint4  ba0, ba1;
        float4 fb0, fb1, fb2, fb3;

#define LOAD_TILE(kt) do {                                                        \
        if constexpr (ABF16) {                                                    \
            if (avalid) { const uint4* p = (const uint4*)(arow_b + (kt));         \
                ba0 = p[0]; ba1 = p[1]; }                                         \
            else { ba0 = make_uint4(0,0,0,0); ba1 = make_uint4(0,0,0,0); }        \
        } else {                                                                  \
            if (avalid) { const float4* p = (const float4*)(arow_f + (kt));       \
                fa0 = p[0]; fa1 = p[1]; fa2 = p[2]; fa3 = p[3]; }                 \
            else { fa0 = fa1 = fa2 = fa3 = make_float4(0.f,0.f,0.f,0.f); }        \
        }                                                                         \
        { const float4* p = (const float4*)(browp + (kt));                        \
          fb0 = p[0]; fb1 = p[1]; fb2 = p[2]; fb3 = p[3]; }                       \
    } while (0)

#define WRITE_TILE(cur) do {                                                      \
        if constexpr (ABF16) {                                                    \
            *(uint4*)&Asl[cur][wo0] = ba0;                                        \
            *(uint4*)&Asl[cur][wo1] = ba1;                                        \
        } else {                                                                  \
            *(uint4*)&Asl[cur][wo0] = pack8(fa0, fa1);                            \
            *(uint4*)&Asl[cur][wo1] = pack8(fa2, fa3);                            \
        }                                                                         \
        *(uint4*)&Bsl[cur][wo0] = pack8(fb0, fb1);                                \
        *(uint4*)&Bsl[cur][wo1] = pack8(fb2, fb3);                                \
    } while (0)

        LOAD_TILE(0);
        WRITE_TILE(0);
        __syncthreads();

        for (int t = 0; t < nk; ++t) {
            const int cur = t & 1;
            if (t + 1 < nk) LOAD_TILE((t + 1) << 5);   // issue next-tile loads (no wait)
            bf16x8 af[4], bfr[4];
            #pragma unroll
            for (int f = 0; f < 4; f++) af[f]  = *(const bf16x8*)&Asl[cur][roA[f]];
            #pragma unroll
            for (int f = 0; f < 4; f++) bfr[f] = *(const bf16x8*)&Bsl[cur][roB[f]];
            #pragma unroll
            for (int mf = 0; mf < 4; mf++)
                #pragma unroll
                for (int nf = 0; nf < 4; nf++)
                    acc[mf][nf] = __builtin_amdgcn_mfma_f32_16x16x32_bf16(
                        af[mf], bfr[nf], acc[mf][nf], 0, 0, 0);
            if (t + 1 < nk) WRITE_TILE(cur ^ 1);       // vmcnt waits land here
            __syncthreads();
        }
#undef LOAD_TILE
#undef WRITE_TILE

        // epilogue — D layout: col = lane&15, row = (lane>>4)*4 + reg
        #pragma unroll
        for (int mf = 0; mf < 4; mf++) {
            #pragma unroll
            for (int j = 0; j < 4; j++) {
                int rl = wm0 + mf * 16 + lk * 4 + j;
                if (mt * 128 + rl < mcnt) {
                    size_t srowg = (size_t)(mbase + mt * 128 + rl);
                    float sc = 1.f;
                    if constexpr (MODE == 1) { if constexpr (GROUPED) sc = slot_wt[srowg]; }
                    int tok = 0;
                    if constexpr (MODE == 3) tok = slot_tok[srowg];
                    float gv = 0.f;
                    if constexpr (MODE == 2) gv = sgate[srowg];
                    #pragma unroll
                    for (int nf = 0; nf < 4; nf++) {
                        int col = blockIdx.x * 128 + wn0 + nf * 16 + lm;
                        float v = acc[mf][nf][j];
                        if constexpr (MODE == 0) {
                            Cbf[srowg * (size_t)N + col] = f2bf(v);
                        } else if constexpr (MODE == 1) {
                            float g  = bf2f(Gbf[srowg * (size_t)N + col]);
                            float sl = g / (1.f + __expf(-g));
                            Cbf[srowg * (size_t)N + col] = f2bf(sl * v * sc);
                        } else if constexpr (MODE == 2) {
                            outF[srowg * (size_t)N + col] = gv * v;
                        } else {
                            atomicAdd(&outF[(size_t)tok * (size_t)N + col], v);
                        }
                    }
                }
            }
        }
    }
}

extern "C" void kernel_launch(void* const* d_in, const int* in_sizes, int n_in,
                              void* d_out, int out_size, void* d_ws, size_t ws_size,
                              hipStream_t stream)
{
    const float* x      = (const float*)d_in[0];
    const float* rw     = (const float*)d_in[1];
    const float* w_gate = (const float*)d_in[2];
    const float* w_up   = (const float*)d_in[3];
    const float* w_down = (const float*)d_in[4];
    const float* sw_g   = (const float*)d_in[5];
    const float* sw_u   = (const float*)d_in[6];
    const float* sw_d   = (const float*)d_in[7];
    const float* sgw    = (const float*)d_in[8];
    float* out = (float*)d_out;

    char* ws = (char*)d_ws;
    int*   cnt      = (int*)(ws + 0);        // 60 ints
    int*   fill     = (int*)(ws + 256);      // 60 ints
    int*   basea    = (int*)(ws + 512);      // 60 ints
    float* sgate    = (float*)(ws + 768);    // 1024 f32
    float* topk_p   = (float*)(ws + 5120);   // 4096 f32
    int*   topk_i   = (int*)(ws + 21504);    // 4096 int
    int*   slot_tok = (int*)(ws + 37888);    // 4096 int
    float* slot_wt  = (float*)(ws + 54272);  // 4096 f32
    u16*   xg = (u16*)(ws + 71680);                    // [4096][1408] bf16
    u16*   h  = xg + (size_t)4096 * ID;                // [4096][1408] bf16
    u16*   sg = h  + (size_t)4096 * ID;                // [1024][5632] bf16
    u16*   hs = sg + (size_t)TT * SID;                 // [1024][5632] bf16

    hipMemsetAsync(ws, 0, 512, stream);  // zero cnt + fill

    router_k<<<TT, 64, 0, stream>>>(x, rw, sgw, topk_p, topk_i, cnt, sgate);
    prefix_k<<<1, 64, 0, stream>>>(cnt, basea);
    scatter_k<<<4, 256, 0, stream>>>(topk_p, topk_i, basea, fill, slot_tok, slot_wt);

    // routed gate: xg = X @ w_gate[e]^T   (K=H, N=I)
    gemm_k<0, false, true><<<dim3(ID / 128, 2, NE), 256, 0, stream>>>(
        x, nullptr, w_gate, (size_t)ID * HD, xg, nullptr, nullptr,
        slot_tok, slot_wt, sgate, cnt, basea, HD, ID, 0);
    // routed up fused SwiGLU: h = silu(xg) * (X @ w_up^T) * combine_w
    gemm_k<1, false, true><<<dim3(ID / 128, 2, NE), 256, 0, stream>>>(
        x, nullptr, w_up, (size_t)ID * HD, h, xg, nullptr,
        slot_tok, slot_wt, sgate, cnt, basea, HD, ID, 0);
    // shared gate: sg = X @ sw_gate^T    (K=H, N=SI)
    gemm_k<0, false, false><<<dim3(SID / 128, TT / 128, 1), 256, 0, stream>>>(
        x, nullptr, sw_g, 0, sg, nullptr, nullptr,
        nullptr, nullptr, nullptr, nullptr, nullptr, HD, SID, TT);
    // shared up fused SwiGLU: hs = silu(sg) * (X @ sw_up^T)
    gemm_k<1, false, false><<<dim3(SID / 128, TT / 128, 1), 256, 0, stream>>>(
        x, nullptr, sw_u, 0, hs, sg, nullptr,
        nullptr, nullptr, nullptr, nullptr, nullptr, HD, SID, TT);
    // shared down + sigmoid gate, overwrites out: out = sigmoid(z) * (hs @ sw_down^T)
    gemm_k<2, true, false><<<dim3(HD / 128, TT / 128, 1), 256, 0, stream>>>(
        nullptr, hs, sw_d, 0, nullptr, nullptr, out,
        nullptr, nullptr, sgate, nullptr, nullptr, SID, HD, TT);
    // routed down, accumulates: out[tok] += h @ w_down[e]^T
    gemm_k<3, true, true><<<dim3(HD / 128, 2, NE), 256, 0, stream>>>(
        nullptr, h, w_down, (size_t)HD * ID, nullptr, nullptr, out,
        slot_tok, slot_wt, sgate, cnt, basea, ID, HD, 0);
}

// Round 3
// 831.861 us; speedup vs baseline: 1.6319x; 1.6319x over previous
//
#include <hip/hip_runtime.h>
#include <hip/hip_bf16.h>

// QwenMoe: T=1024 H=2048 I=1408 E=60 SI=5632 topk=4, fp32 in/out.
// R3: global_load_lds DMA staging (fp32 tiles in LDS, linear dest +
// inverse-swizzled global source per rule #21), T3-minimum 2-phase dbuf,
// BN=64 tiles, fused gate+up (no xg round-trip), K-split on shared-down.

typedef float  f32x4  __attribute__((ext_vector_type(4)));
typedef short  bf16x8 __attribute__((ext_vector_type(8)));
typedef unsigned short u16;
typedef unsigned int   u32;

constexpr int TT = 1024, HD = 2048, ID = 1408, NE = 60, SID = 5632, KTOP = 4;

#define GLDS(g, l) __builtin_amdgcn_global_load_lds( \
    (const __attribute__((address_space(1))) void*)(g), \
    (__attribute__((address_space(3))) void*)(l), 16, 0, 0)

__device__ __forceinline__ u16 f2bf(float f) {
    union { float f; u32 u; } v; v.f = f;
    u32 r = v.u + 0x7FFFu + ((v.u >> 16) & 1u);   // RNE
    return (u16)(r >> 16);
}
__device__ __forceinline__ u32 cvtpk(float a, float b) {
    u32 r; asm("v_cvt_pk_bf16_f32 %0, %1, %2" : "=v"(r) : "v"(a), "v"(b));
    return r;
}
// fp32 tile [R][32], chunk-swizzled: logical 16B-chunk q of row r lives at
// chunk q ^ ((r&3)<<1). Read 8 k-floats, convert to bf16x8.
__device__ __forceinline__ bf16x8 fragF32(const float* tile, int r, int lk) {
    const float4* p = (const float4*)(tile + r * 32 + (((lk << 1) ^ ((r & 3) << 1)) << 2));
    float4 a = p[0], b = p[1];
    union { u32 u[4]; bf16x8 v; } rr;
    rr.u[0] = cvtpk(a.x, a.y); rr.u[1] = cvtpk(a.z, a.w);
    rr.u[2] = cvtpk(b.x, b.y); rr.u[3] = cvtpk(b.z, b.w);
    return rr.v;
}
// bf16 tile [R][32], chunk q of row r at q ^ (r&3).
__device__ __forceinline__ bf16x8 fragB16(const u16* tile, int r, int lk) {
    return *(const bf16x8*)(tile + r * 32 + ((lk ^ (r & 3)) << 3));
}

// ---------------- router ----------------
__global__ __launch_bounds__(64) void router_k(
    const float* __restrict__ x, const float* __restrict__ rw,
    const float* __restrict__ sgw,
    float* __restrict__ topk_p, int* __restrict__ topk_i,
    int* __restrict__ cnt, float* __restrict__ sgate)
{
    const int t = blockIdx.x, l = threadIdx.x;
    const float4* xr = ((const float4*)(x + (size_t)t * HD)) + l * 8;
    float4 xa[8];
    #pragma unroll
    for (int i = 0; i < 8; i++) xa[i] = xr[i];

    float le = 0.f;
    for (int e = 0; e < NE; e++) {
        const float4* wr = ((const float4*)(rw + (size_t)e * HD)) + l * 8;
        float a = 0.f;
        #pragma unroll
        for (int i = 0; i < 8; i++) {
            float4 wv = wr[i];
            a += xa[i].x * wv.x + xa[i].y * wv.y + xa[i].z * wv.z + xa[i].w * wv.w;
        }
        #pragma unroll
        for (int s = 32; s; s >>= 1) a += __shfl_xor(a, s);
        if (l == e) le = a;
    }
    {
        const float4* wr = ((const float4*)sgw) + l * 8;
        float a = 0.f;
        #pragma unroll
        for (int i = 0; i < 8; i++) {
            float4 wv = wr[i];
            a += xa[i].x * wv.x + xa[i].y * wv.y + xa[i].z * wv.z + xa[i].w * wv.w;
        }
        #pragma unroll
        for (int s = 32; s; s >>= 1) a += __shfl_xor(a, s);
        if (l == 0) sgate[t] = 1.f / (1.f + __expf(-a));
    }
    float mv = (l < NE) ? le : -3.4e38f;
    #pragma unroll
    for (int s = 32; s; s >>= 1) mv = fmaxf(mv, __shfl_xor(mv, s));
    float p = (l < NE) ? __expf(le - mv) : 0.f;
    float ss = p;
    #pragma unroll
    for (int s = 32; s; s >>= 1) ss += __shfl_xor(ss, s);
    p /= ss;
    float pv = (l < NE) ? p : -1.f;
    int   pi = l;
    float kp = 0.f; int ki = 0;
    for (int k = 0; k < KTOP; k++) {
        float bv = pv; int bi = pi;
        #pragma unroll
        for (int s = 32; s; s >>= 1) {
            float ov = __shfl_xor(bv, s); int oi = __shfl_xor(bi, s);
            if (ov > bv || (ov == bv && oi < bi)) { bv = ov; bi = oi; }
        }
        if (l == k) { kp = bv; ki = bi; }
        if (pi == bi) pv = -1.f;
    }
    if (l < KTOP) {
        topk_p[t * KTOP + l] = kp;
        topk_i[t * KTOP + l] = ki;
        atomicAdd(&cnt[ki], 1);
    }
}

__global__ __launch_bounds__(64) void prefix_k(const int* __restrict__ cnt, int* __restrict__ base)
{
    int l = threadIdx.x;
    if (l < NE) {
        int s = 0;
        for (int j = 0; j < l; j++) s += cnt[j];
        base[l] = s;
    }
}

__global__ __launch_bounds__(256) void scatter_k(
    const float* __restrict__ topk_p, const int* __restrict__ topk_i,
    const int* __restrict__ base, int* __restrict__ fill,
    int* __restrict__ slot_tok, float* __restrict__ slot_wt)
{
    int t = blockIdx.x * blockDim.x + threadIdx.x;
    if (t >= TT) return;
    for (int k = 0; k < KTOP; k++) {
        int e = topk_i[t * KTOP + k];
        int pos = atomicAdd(&fill[e], 1);
        int s = base[e] + pos;
        slot_tok[s] = t;
        slot_wt[s]  = topk_p[t * KTOP + k];
    }
}

// ------- fused gate+up: H = silu(X@Wg^T) * (X@Wu^T) * wt, tile 128Mx64N -------
template<bool GROUPED>
__global__ __launch_bounds__(256, 2) void gu_k(
    const float* __restrict__ X,
    const float* __restrict__ Wg, const float* __restrict__ Wu, size_t bStride,
    u16* __restrict__ H,
    const int* __restrict__ slot_tok, const float* __restrict__ slot_wt,
    const int* __restrict__ cnt, const int* __restrict__ basearr,
    int K, int N)
{
    __shared__ float Asl[2][128 * 32];
    __shared__ float Bgsl[2][64 * 32];
    __shared__ float Busl[2][64 * 32];
    const int tid = threadIdx.x, w = tid >> 6, lane = tid & 63;
    const int lm = lane & 15, lk = lane >> 4, wm0 = w * 32;
    const int e = GROUPED ? blockIdx.z : 0;
    const int mcnt = GROUPED ? cnt[e] : 128;
    const int mbase = GROUPED ? basearr[e] : blockIdx.y * 128;
    const float* Bg = Wg + (size_t)e * bStride + (size_t)blockIdx.x * 64 * K;
    const float* Bu = Wu + (size_t)e * bStride + (size_t)blockIdx.x * 64 * K;
    // inverse swizzle baked into per-lane global source offset (lane-constant)
    const int aofs = ((lane & 7) ^ (((lane >> 3) & 3) << 1)) << 2;
    const float* bgrow[2]; const float* burow[2];
    #pragma unroll
    for (int j = 0; j < 2; j++) {
        int rB = w * 16 + j * 8 + (lane >> 3);
        bgrow[j] = Bg + (size_t)rB * K + aofs;
        burow[j] = Bu + (size_t)rB * K + aofs;
    }
    const int nk = K >> 5;

    for (int mt = 0; GROUPED ? (mt * 128 < mcnt) : (mt == 0); ++mt) {
        const float* arow[4];
        #pragma unroll
        for (int j = 0; j < 4; j++) {
            int rA = w * 32 + j * 8 + (lane >> 3);
            int row;
            if constexpr (GROUPED) {
                int sl = mbase + mt * 128 + rA;
                row = (mt * 128 + rA < mcnt) ? slot_tok[sl] : 0;
            } else row = mbase + rA;
            arow[j] = X + (size_t)row * K + aofs;
        }
        f32x4 ag[2][4], au[2][4];
        #pragma unroll
        for (int mf = 0; mf < 2; mf++)
            #pragma unroll
            for (int nf = 0; nf < 4; nf++) {
                ag[mf][nf] = f32x4{0.f, 0.f, 0.f, 0.f};
                au[mf][nf] = f32x4{0.f, 0.f, 0.f, 0.f};
            }

        auto stage = [&](int b, int kt) {
            #pragma unroll
            for (int j = 0; j < 4; j++)
                GLDS(arow[j] + kt, &Asl[b][w * 1024 + j * 256]);
            #pragma unroll
            for (int j = 0; j < 2; j++) {
                GLDS(bgrow[j] + kt, &Bgsl[b][w * 512 + j * 256]);
                GLDS(burow[j] + kt, &Busl[b][w * 512 + j * 256]);
            }
        };

        stage(0, 0);
        __syncthreads();                       // vmcnt(0) drain + barrier
        int cur = 0;
        for (int t = 0; t < nk; ++t) {
            if (t + 1 < nk) stage(cur ^ 1, (t + 1) << 5);   // fire-and-forget DMA
            const float* At  = &Asl[cur][0];
            const float* Bgt = &Bgsl[cur][0];
            const float* But = &Busl[cur][0];
            bf16x8 afr[2];
            #pragma unroll
            for (int mf = 0; mf < 2; mf++) afr[mf] = fragF32(At, wm0 + mf * 16 + lm, lk);
            #pragma unroll
            for (int nf = 0; nf < 4; nf++) {
                bf16x8 bgf = fragF32(Bgt, nf * 16 + lm, lk);
                bf16x8 buf_ = fragF32(But, nf * 16 + lm, lk);
                #pragma unroll
                for (int mf = 0; mf < 2; mf++) {
                    ag[mf][nf] = __builtin_amdgcn_mfma_f32_16x16x32_bf16(afr[mf], bgf, ag[mf][nf], 0, 0, 0);
                    au[mf][nf] = __builtin_amdgcn_mfma_f32_16x16x32_bf16(afr[mf], buf_, au[mf][nf], 0, 0, 0);
                }
            }
            __syncthreads();                   // drains next tile's DMA + barrier
            cur ^= 1;
        }

        // epilogue: silu(gate_f32) * up * wt -> bf16 H
        #pragma unroll
        for (int mf = 0; mf < 2; mf++)
            #pragma unroll
            for (int j = 0; j < 4; j++) {
                int m = wm0 + mf * 16 + lk * 4 + j;
                bool valid = GROUPED ? (mt * 128 + m < mcnt) : true;
                if (valid) {
                    size_t row; float wt;
                    if constexpr (GROUPED) {
                        size_t sl = (size_t)(mbase + mt * 128 + m);
                        row = sl; wt = slot_wt[sl];
                    } else { row = (size_t)(mbase + m); wt = 1.f; }
                    #pragma unroll
                    for (int nf = 0; nf < 4; nf++) {
                        int col = blockIdx.x * 64 + nf * 16 + lm;
                        float g = ag[mf][nf][j], u = au[mf][nf][j];
                        float hv = g / (1.f + __expf(-g)) * u * wt;
                        H[row * (size_t)N + col] = f2bf(hv);
                    }
                }
            }
    }
}

// ------- down proj: out[tok] += scale * (Hb @ W^T), tile 128Mx64N, atomic -------
template<bool GROUPED>
__global__ __launch_bounds__(256, 4) void down_k(
    const u16* __restrict__ Hb, const float* __restrict__ W0, size_t bStride,
    float* __restrict__ outF,
    const int* __restrict__ slot_tok, const float* __restrict__ sgate,
    const int* __restrict__ cnt, const int* __restrict__ basearr,
    int K, int kspan, int N)
{
    __shared__ u16   Asl[2][128 * 32];
    __shared__ float Bsl[2][64 * 32];
    const int tid = threadIdx.x, w = tid >> 6, lane = tid & 63;
    const int lm = lane & 15, lk = lane >> 4, wm0 = w * 32;
    const int e = GROUPED ? blockIdx.z : 0;
    const int mcnt = GROUPED ? cnt[e] : 128;
    const int mbase = GROUPED ? basearr[e] : blockIdx.y * 128;
    const int kbeg = GROUPED ? 0 : blockIdx.z * kspan;
    const int nk = (GROUPED ? K : kspan) >> 5;
    const float* Bp = W0 + (size_t)e * bStride + (size_t)blockIdx.x * 64 * K + kbeg;
    const int aofsF = ((lane & 7) ^ (((lane >> 3) & 3) << 1)) << 2;
    const int aofsH = ((lane & 3) ^ ((lane >> 2) & 3)) << 3;
    const float* brow[2];
    #pragma unroll
    for (int j = 0; j < 2; j++) {
        int rB = w * 16 + j * 8 + (lane >> 3);
        brow[j] = Bp + (size_t)rB * K + aofsF;
    }

    for (int mt = 0; GROUPED ? (mt * 128 < mcnt) : (mt == 0); ++mt) {
        const u16* arow[2];
        #pragma unroll
        for (int j = 0; j < 2; j++) {
            int rA = w * 32 + j * 16 + (lane >> 2);
            int row;
            if constexpr (GROUPED) {
                row = (mt * 128 + rA < mcnt) ? (mbase + mt * 128 + rA) : mbase;
            } else row = mbase + rA;
            arow[j] = Hb + (size_t)row * K + kbeg + aofsH;
        }
        f32x4 acc[2][4];
        #pragma unroll
        for (int mf = 0; mf < 2; mf++)
            #pragma unroll
            for (int nf = 0; nf < 4; nf++) acc[mf][nf] = f32x4{0.f, 0.f, 0.f, 0.f};

        auto stage = [&](int b, int kt) {
            #pragma unroll
            for (int j = 0; j < 2; j++)
                GLDS(arow[j] + kt, &Asl[b][w * 1024 + j * 512]);
            #pragma unroll
            for (int j = 0; j < 2; j++)
                GLDS(brow[j] + kt, &Bsl[b][w * 512 + j * 256]);
        };

        stage(0, 0);
        __syncthreads();
        int cur = 0;
        for (int t = 0; t < nk; ++t) {
            if (t + 1 < nk) stage(cur ^ 1, (t + 1) << 5);
            const u16*   At = &Asl[cur][0];
            const float* Bt = &Bsl[cur][0];
            bf16x8 afr[2];
            #pragma unroll
            for (int mf = 0; mf < 2; mf++) afr[mf] = fragB16(At, wm0 + mf * 16 + lm, lk);
            #pragma unroll
            for (int nf = 0; nf < 4; nf++) {
                bf16x8 bfr = fragF32(Bt, nf * 16 + lm, lk);
                #pragma unroll
                for (int mf = 0; mf < 2; mf++)
                    acc[mf][nf] = __builtin_amdgcn_mfma_f32_16x16x32_bf16(afr[mf], bfr, acc[mf][nf], 0, 0, 0);
            }
            __syncthreads();
            cur ^= 1;
        }

        #pragma unroll
        for (int mf = 0; mf < 2; mf++)
            #pragma unroll
            for (int j = 0; j < 4; j++) {
                int m = wm0 + mf * 16 + lk * 4 + j;
                bool valid = GROUPED ? (mt * 128 + m < mcnt) : true;
                if (valid) {
                    int tok; float scale;
                    if constexpr (GROUPED) {
                        tok = slot_tok[mbase + mt * 128 + m]; scale = 1.f;
                    } else { tok = mbase + m; scale = sgate[tok]; }
                    #pragma unroll
                    for (int nf = 0; nf < 4; nf++) {
                        int col = blockIdx.x * 64 + nf * 16 + lm;
                        atomicAdd(&outF[(size_t)tok * N + col], scale * acc[mf][nf][j]);
                    }
                }
            }
    }
}

extern "C" void kernel_launch(void* const* d_in, const int* in_sizes, int n_in,
                              void* d_out, int out_size, void* d_ws, size_t ws_size,
                              hipStream_t stream)
{
    const float* x      = (const float*)d_in[0];
    const float* rw     = (const float*)d_in[1];
    const float* w_gate = (const float*)d_in[2];
    const float* w_up   = (const float*)d_in[3];
    const float* w_down = (const float*)d_in[4];
    const float* sw_g   = (const float*)d_in[5];
    const float* sw_u   = (const float*)d_in[6];
    const float* sw_d   = (const float*)d_in[7];
    const float* sgw    = (const float*)d_in[8];
    float* out = (float*)d_out;

    char* ws = (char*)d_ws;
    int*   cnt      = (int*)(ws + 0);
    int*   fill     = (int*)(ws + 256);
    int*   basea    = (int*)(ws + 512);
    float* sgate    = (float*)(ws + 768);
    float* topk_p   = (float*)(ws + 5120);
    int*   topk_i   = (int*)(ws + 21504);
    int*   slot_tok = (int*)(ws + 37888);
    float* slot_wt  = (float*)(ws + 54272);
    u16*   h  = (u16*)(ws + 71680);            // [4096][1408] bf16
    u16*   hs = h + (size_t)4096 * ID;         // [1024][5632] bf16

    hipMemsetAsync(ws, 0, 512, stream);                          // cnt + fill
    hipMemsetAsync(d_out, 0, (size_t)TT * HD * sizeof(float), stream);

    router_k<<<TT, 64, 0, stream>>>(x, rw, sgw, topk_p, topk_i, cnt, sgate);
    prefix_k<<<1, 64, 0, stream>>>(cnt, basea);
    scatter_k<<<4, 256, 0, stream>>>(topk_p, topk_i, basea, fill, slot_tok, slot_wt);

    // routed fused gate+up -> h (bf16, slot-indexed), weight = slot_wt
    gu_k<true><<<dim3(ID / 64, 1, NE), 256, 0, stream>>>(
        x, w_gate, w_up, (size_t)ID * HD, h,
        slot_tok, slot_wt, cnt, basea, HD, ID);
    // shared fused gate+up -> hs (bf16, token-indexed)
    gu_k<false><<<dim3(SID / 64, TT / 128, 1), 256, 0, stream>>>(
        x, sw_g, sw_u, 0, hs,
        nullptr, nullptr, nullptr, nullptr, HD, SID);
    // routed down: out[tok] += h @ w_down[e]^T
    down_k<true><<<dim3(HD / 64, 1, NE), 256, 0, stream>>>(
        h, w_down, (size_t)HD * ID, out,
        slot_tok, nullptr, cnt, basea, ID, 0, HD);
    // shared down (K split in 2): out[tok] += sigmoid_gate * (hs @ sw_down^T)
    down_k<false><<<dim3(HD / 64, TT / 128, 2), 256, 0, stream>>>(
        hs, sw_d, 0, out,
        nullptr, sgate, nullptr, nullptr, SID, SID / 2, HD);
}